// Round 1
// baseline (495.494 us; speedup 1.0000x reference)
//
#include <hip/hip_runtime.h>

#define NUM_GRAPHS 512
#define EPS 1e-5f
#define CHN 128          // channels
#define CHN4 32          // channels as float4

__device__ __forceinline__ int lower_bound_i(const int* __restrict__ b, int n, int val) {
    int l = 0, r = n;
    while (l < r) {
        int m = (l + r) >> 1;
        if (b[m] < val) l = m + 1; else r = m;
    }
    return l;
}

__global__ __launch_bounds__(256) void gln_kernel(
    const float* __restrict__ x,
    const int* __restrict__ batch,
    const float* __restrict__ weight,
    const float* __restrict__ bias,
    float* __restrict__ out,
    int N)
{
    const int s   = blockIdx.x;     // segment id
    const int tid = threadIdx.x;
    const int q   = tid & 31;       // float4 column index (channels 4q..4q+3)
    const int g   = tid >> 5;       // row group 0..7

    // Segment boundaries (uniform across the block; sorted batch array).
    const int lo = lower_bound_i(batch, N, s);
    const int hi = lower_bound_i(batch, N, s + 1);

    const float4* __restrict__ x4 = (const float4*)x;
    float4*       __restrict__ o4 = (float4*)out;

    // ---- Phase 1: per-channel sum / sumsq over rows [lo, hi) ----
    float4 sum = make_float4(0.f, 0.f, 0.f, 0.f);
    float4 sq  = make_float4(0.f, 0.f, 0.f, 0.f);
    for (int row = lo + g; row < hi; row += 8) {
        float4 v = x4[(size_t)row * CHN4 + q];
        sum.x += v.x; sum.y += v.y; sum.z += v.z; sum.w += v.w;
        sq.x  += v.x * v.x; sq.y += v.y * v.y; sq.z += v.z * v.z; sq.w += v.w * v.w;
    }

    __shared__ float4 s_sum[256];
    __shared__ float4 s_sq[256];
    s_sum[tid] = sum; s_sq[tid] = sq;
    __syncthreads();

    // Tree-reduce across the 8 row groups (stride in units of 32 threads).
    for (int off = 128; off >= 32; off >>= 1) {
        if (tid < off) {
            float4 a = s_sum[tid], b = s_sum[tid + off];
            a.x += b.x; a.y += b.y; a.z += b.z; a.w += b.w;
            s_sum[tid] = a;
            float4 c = s_sq[tid], d = s_sq[tid + off];
            c.x += d.x; c.y += d.y; c.z += d.z; c.w += d.w;
            s_sq[tid] = c;
        }
        __syncthreads();
    }

    // Lanes 0..31: finalize mean / inv_std, broadcast via the same LDS arrays.
    if (tid < 32) {
        float cnt = (float)(hi - lo);
        float inv_cnt = 1.f / fmaxf(cnt, 1.f);
        float4 m = s_sum[tid];
        m.x *= inv_cnt; m.y *= inv_cnt; m.z *= inv_cnt; m.w *= inv_cnt;
        float4 e2 = s_sq[tid];
        float4 inv;
        inv.x = rsqrtf(e2.x * inv_cnt - m.x * m.x + EPS);
        inv.y = rsqrtf(e2.y * inv_cnt - m.y * m.y + EPS);
        inv.z = rsqrtf(e2.z * inv_cnt - m.z * m.z + EPS);
        inv.w = rsqrtf(e2.w * inv_cnt - m.w * m.w + EPS);
        s_sum[tid] = m;      // broadcast mean
        s_sq[tid]  = inv;    // broadcast inv_std
    }
    __syncthreads();

    const float4 m4 = s_sum[q];
    const float4 i4 = s_sq[q];
    const float4 w4 = ((const float4*)weight)[q];
    const float4 b4 = ((const float4*)bias)[q];

    // ---- Phase 2: normalize + affine, coalesced float4 writes ----
    for (int row = lo + g; row < hi; row += 8) {
        size_t idx = (size_t)row * CHN4 + q;
        float4 v = x4[idx];
        float4 r;
        r.x = (v.x - m4.x) * i4.x * w4.x + b4.x;
        r.y = (v.y - m4.y) * i4.y * w4.y + b4.y;
        r.z = (v.z - m4.z) * i4.z * w4.z + b4.z;
        r.w = (v.w - m4.w) * i4.w * w4.w + b4.w;
        o4[idx] = r;
    }
}

extern "C" void kernel_launch(void* const* d_in, const int* in_sizes, int n_in,
                              void* d_out, int out_size, void* d_ws, size_t ws_size,
                              hipStream_t stream) {
    const float* x      = (const float*)d_in[0];
    const int*   batch  = (const int*)d_in[1];
    const float* weight = (const float*)d_in[2];
    const float* bias   = (const float*)d_in[3];
    float*       out    = (float*)d_out;
    const int N = in_sizes[0] / CHN;   // 500000

    gln_kernel<<<NUM_GRAPHS, 256, 0, stream>>>(x, batch, weight, bias, out, N);
}

// Round 2
// 488.427 us; speedup vs baseline: 1.0145x; 1.0145x over previous
//
#include <hip/hip_runtime.h>

#define NUM_GRAPHS 512
#define EPS 1e-5f
#define CHN 128          // channels
#define CHN4 32          // channels as float4
#define PORTIONS 8       // sub-blocks per segment in stage 1

__device__ __forceinline__ int lower_bound_i(const int* __restrict__ b, int n, int val) {
    int l = 0, r = n;
    while (l < r) {
        int m = (l + r) >> 1;
        if (b[m] < val) l = m + 1; else r = m;
    }
    return l;
}

// ---------------- Stage 1: per-(segment, portion) partial sums ----------------
// grid = NUM_GRAPHS * PORTIONS blocks, 256 threads.
// ws_part layout (float4): [(s*PORTIONS+p)*64 + 0..31] = sum, [+32..63] = sumsq
__global__ __launch_bounds__(256) void gln_stage1(
    const float* __restrict__ x,
    const int* __restrict__ batch,
    float* __restrict__ ws_part,
    int N)
{
    const int s   = blockIdx.x >> 3;       // segment
    const int p   = blockIdx.x & (PORTIONS - 1);
    const int tid = threadIdx.x;
    const int q   = tid & 31;              // float4 column
    const int g   = tid >> 5;              // row group 0..7

    const int lo = lower_bound_i(batch, N, s);
    const int hi = lower_bound_i(batch, N, s + 1);

    const float4* __restrict__ x4 = (const float4*)x;

    float4 sum = make_float4(0.f, 0.f, 0.f, 0.f);
    float4 sq  = make_float4(0.f, 0.f, 0.f, 0.f);
    // portion p covers rows lo + 8p + 64k + g : 8 consecutive rows (4 KB) per iter
    for (int row = lo + p * 8 + g; row < hi; row += 64) {
        float4 v = x4[(size_t)row * CHN4 + q];
        sum.x += v.x; sum.y += v.y; sum.z += v.z; sum.w += v.w;
        sq.x  += v.x * v.x; sq.y += v.y * v.y; sq.z += v.z * v.z; sq.w += v.w * v.w;
    }

    __shared__ float4 s_sum[256];
    __shared__ float4 s_sq[256];
    s_sum[tid] = sum; s_sq[tid] = sq;
    __syncthreads();

    for (int off = 128; off >= 32; off >>= 1) {
        if (tid < off) {
            float4 a = s_sum[tid], b = s_sum[tid + off];
            a.x += b.x; a.y += b.y; a.z += b.z; a.w += b.w;
            s_sum[tid] = a;
            float4 c = s_sq[tid], d = s_sq[tid + off];
            c.x += d.x; c.y += d.y; c.z += d.z; c.w += d.w;
            s_sq[tid] = c;
        }
        __syncthreads();
    }

    float4* out4 = (float4*)ws_part + (size_t)blockIdx.x * 64;
    if (tid < 32) out4[tid] = s_sum[tid];
    else if (tid < 64) out4[tid] = s_sq[tid - 32];
}

// ---------------- Stage 2: finalize stats -> scale/shift ----------------
// grid = NUM_GRAPHS blocks, 128 threads (one per channel).
// ws_stats layout (float): [s*256 + c] = scale, [s*256 + 128 + c] = shift
__global__ __launch_bounds__(128) void gln_finalize(
    const float* __restrict__ ws_part,
    const int* __restrict__ batch,
    const float* __restrict__ weight,
    const float* __restrict__ bias,
    float* __restrict__ ws_stats,
    int N)
{
    const int s = blockIdx.x;
    const int c = threadIdx.x;

    const int lo = lower_bound_i(batch, N, s);
    const int hi = lower_bound_i(batch, N, s + 1);

    float sum = 0.f, sq = 0.f;
    const float* base = ws_part + (size_t)s * PORTIONS * 256;
    #pragma unroll
    for (int p = 0; p < PORTIONS; ++p) {
        sum += base[p * 256 + c];
        sq  += base[p * 256 + 128 + c];
    }
    float inv_cnt = 1.f / fmaxf((float)(hi - lo), 1.f);
    float mean = sum * inv_cnt;
    float inv_std = rsqrtf(sq * inv_cnt - mean * mean + EPS);
    float scale = inv_std * weight[c];
    float shift = bias[c] - mean * scale;
    ws_stats[(size_t)s * 256 + c]       = scale;
    ws_stats[(size_t)s * 256 + 128 + c] = shift;
}

// ---------------- Stage 3: normalize ----------------
// grid-stride over all N*CHN4 float4 elements. out = x*scale + shift.
__global__ __launch_bounds__(256) void gln_normalize(
    const float* __restrict__ x,
    const int* __restrict__ batch,
    const float* __restrict__ ws_stats,
    float* __restrict__ out,
    int N)
{
    const float4* __restrict__ x4 = (const float4*)x;
    const float4* __restrict__ st4 = (const float4*)ws_stats;
    float4* __restrict__ o4 = (float4*)out;

    const size_t total = (size_t)N * CHN4;
    size_t e = (size_t)blockIdx.x * blockDim.x + threadIdx.x;
    const size_t stride = (size_t)gridDim.x * blockDim.x;

    for (; e < total; e += stride) {
        int row = (int)(e >> 5);
        int q   = (int)(e & 31);
        int seg = batch[row];
        float4 sc = st4[(size_t)seg * 64 + q];
        float4 sh = st4[(size_t)seg * 64 + 32 + q];
        float4 v  = x4[e];
        float4 r;
        r.x = fmaf(v.x, sc.x, sh.x);
        r.y = fmaf(v.y, sc.y, sh.y);
        r.z = fmaf(v.z, sc.z, sh.z);
        r.w = fmaf(v.w, sc.w, sh.w);
        o4[e] = r;
    }
}

extern "C" void kernel_launch(void* const* d_in, const int* in_sizes, int n_in,
                              void* d_out, int out_size, void* d_ws, size_t ws_size,
                              hipStream_t stream) {
    const float* x      = (const float*)d_in[0];
    const int*   batch  = (const int*)d_in[1];
    const float* weight = (const float*)d_in[2];
    const float* bias   = (const float*)d_in[3];
    float*       out    = (float*)d_out;
    const int N = in_sizes[0] / CHN;   // 500000

    float* ws_part  = (float*)d_ws;                                  // 512*8*256 floats = 4 MB
    float* ws_stats = ws_part + (size_t)NUM_GRAPHS * PORTIONS * 256; // 512*256 floats = 512 KB

    gln_stage1<<<NUM_GRAPHS * PORTIONS, 256, 0, stream>>>(x, batch, ws_part, N);
    gln_finalize<<<NUM_GRAPHS, 128, 0, stream>>>(ws_part, batch, weight, bias, ws_stats, N);

    const size_t total4 = (size_t)N * CHN4;
    int nblocks = (int)((total4 + 256 * 4 - 1) / (256 * 4));         // ~4 float4 per thread
    gln_normalize<<<nblocks, 256, 0, stream>>>(x, batch, ws_stats, out, N);
}